// Round 1
// 8918.786 us; speedup vs baseline: 1.5103x; 1.5103x over previous
//
#include <hip/hip_runtime.h>
#include <hip/hip_bf16.h>
#include <stddef.h>

// Problem constants
#define BB 128     // batch
#define LL 64      // feature pixels
#define TT 20      // decode steps
#define VV 32000   // vocab
#define EE 512     // embed
#define HH 1024    // hidden
#define AA 512     // attn dim
#define FF 2048    // num_features

// ---------------------------------------------------------------------------
// mean over L axis: mean_ann[b,f] = (1/L) sum_l X[b,l,f]
__global__ __launch_bounds__(256) void mean_kernel(const float* __restrict__ X,
                                                   float* __restrict__ mean_ann) {
    int idx = blockIdx.x * 256 + threadIdx.x;    // over B*F
    int b = idx >> 11, f = idx & (FF - 1);
    const float* p = X + (size_t)b * LL * FF + f;
    float s = 0.f;
    #pragma unroll
    for (int l = 0; l < LL; ++l) s += p[l * FF];
    mean_ann[idx] = s * (1.0f / LL);
}

// ---------------------------------------------------------------------------
// 128x128 block-tile fp32 GEMM, 256 threads, TM=TN=8 (split quadrants),
// BK=32, optional K-split over gridDim.z (partials written to C region when
// bias == nullptr; final write with bias when bias != nullptr, gridDim.z==1).
// MODE 0: A fp32 contiguous [M][K]
// MODE 2: A = [emb(y[:,t]) | context | h] row-concat sources, W = [w_ih ; w_hh]
// MODE 3: plain A, W = [sm_w | lm_w] column-concat (each [K][1024])
template<int MODE>
__global__ __launch_bounds__(256, 2)
void gemm128(const float* __restrict__ A,
             const float* __restrict__ ctx, const float* __restrict__ hptr,
             const float* __restrict__ emb, const int* __restrict__ y, int t,
             const float* __restrict__ W, const float* __restrict__ W2,
             const float* __restrict__ bias,
             float* __restrict__ C, int N, int K, int Cstride)
{
    __shared__ float la[32][132];   // k-major A tile (128 rows -> cols)
    __shared__ float lw[32][132];   // W tile rows k, cols n
    const int tid  = threadIdx.x;
    const int nblk = blockIdx.x * 128;
    const int mblk = blockIdx.y * 128;
    const int kchunk = K / (int)gridDim.z;
    const int k0 = blockIdx.z * kchunk;

    const int tn = (tid & 15) * 4;    // cols tn..tn+3 and tn+64..tn+67
    const int tm = (tid >> 4) * 4;    // rows tm..tm+3 and tm+64..tm+67

    float acc[2][2][4][4];
    #pragma unroll
    for (int a = 0; a < 2; ++a)
        #pragma unroll
        for (int b = 0; b < 2; ++b)
            #pragma unroll
            for (int i = 0; i < 4; ++i)
                #pragma unroll
                for (int j = 0; j < 4; ++j) acc[a][b][i][j] = 0.f;

    for (int kc = k0; kc < k0 + kchunk; kc += 32) {
        // ---- stage A tile (128 x 32), transposed to k-major ----
        if constexpr (MODE == 2) {
            // sources: gk<512 emb | gk<2560 context | else h   (boundaries are
            // multiples of 32 -> branch is wave-uniform per staging step)
            #pragma unroll
            for (int i = 0; i < 16; ++i) {
                int e = i * 256 + tid;
                int m = e >> 5, j = e & 31;
                int gk = kc + j;
                float v;
                if (gk < EE)            v = emb[(size_t)y[m * (TT + 1) + t] * EE + gk];
                else if (gk < EE + FF)  v = ctx[(size_t)m * FF + (gk - EE)];
                else                    v = hptr[(size_t)m * HH + (gk - EE - FF)];
                la[j][m] = v;
            }
        } else {
            #pragma unroll
            for (int i = 0; i < 4; ++i) {
                int q = i * 256 + tid;          // 1024 float4
                int m = q >> 3;                  // row 0..127 (8 float4 per row)
                int j4 = (q & 7) * 4;            // k offset
                float4 v = *reinterpret_cast<const float4*>(
                    &A[(size_t)(mblk + m) * K + kc + j4]);
                la[j4 + 0][m] = v.x; la[j4 + 1][m] = v.y;
                la[j4 + 2][m] = v.z; la[j4 + 3][m] = v.w;
            }
        }
        // ---- stage W tile (32 x 128) ----
        #pragma unroll
        for (int i = 0; i < 4; ++i) {
            int q = i * 256 + tid;               // 1024 float4
            int j = q >> 5;                       // row 0..31 (32 float4 per row)
            int n4 = (q & 31) * 4;
            int gk = kc + j;
            int col = nblk + n4;
            const float* wp;
            if constexpr (MODE == 2)
                wp = (gk < EE + FF) ? (W  + (size_t)gk * N + col)
                                    : (W2 + (size_t)(gk - EE - FF) * N + col);
            else if constexpr (MODE == 3)
                wp = (col < HH) ? (W  + (size_t)gk * HH + col)
                                : (W2 + (size_t)gk * HH + (col - HH));
            else
                wp = W + (size_t)gk * N + col;
            *reinterpret_cast<float4*>(&lw[j][n4]) =
                *reinterpret_cast<const float4*>(wp);
        }
        __syncthreads();
        #pragma unroll 4
        for (int k = 0; k < 32; ++k) {
            float4 a0 = *reinterpret_cast<const float4*>(&la[k][tm]);
            float4 a1 = *reinterpret_cast<const float4*>(&la[k][tm + 64]);
            float4 b0 = *reinterpret_cast<const float4*>(&lw[k][tn]);
            float4 b1 = *reinterpret_cast<const float4*>(&lw[k][tn + 64]);
            float am[2][4] = {{a0.x, a0.y, a0.z, a0.w}, {a1.x, a1.y, a1.z, a1.w}};
            float bn[2][4] = {{b0.x, b0.y, b0.z, b0.w}, {b1.x, b1.y, b1.z, b1.w}};
            #pragma unroll
            for (int mh = 0; mh < 2; ++mh)
                #pragma unroll
                for (int i = 0; i < 4; ++i)
                    #pragma unroll
                    for (int nh = 0; nh < 2; ++nh)
                        #pragma unroll
                        for (int j = 0; j < 4; ++j)
                            acc[mh][nh][i][j] =
                                fmaf(am[mh][i], bn[nh][j], acc[mh][nh][i][j]);
        }
        __syncthreads();
    }

    if (bias != nullptr) {
        // final write (gridDim.z == 1)
        #pragma unroll
        for (int mh = 0; mh < 2; ++mh)
            #pragma unroll
            for (int i = 0; i < 4; ++i) {
                size_t gm = (size_t)(mblk + mh * 64 + tm + i);
                #pragma unroll
                for (int nh = 0; nh < 2; ++nh) {
                    int gn = nblk + nh * 64 + tn;
                    float4 bv = *reinterpret_cast<const float4*>(&bias[gn]);
                    float4 r;
                    r.x = acc[mh][nh][i][0] + bv.x;
                    r.y = acc[mh][nh][i][1] + bv.y;
                    r.z = acc[mh][nh][i][2] + bv.z;
                    r.w = acc[mh][nh][i][3] + bv.w;
                    *reinterpret_cast<float4*>(&C[gm * (size_t)Cstride + gn]) = r;
                }
            }
    } else {
        // partial write: C is a region of gridDim.z slabs of [M][N]
        float* P = C + (size_t)blockIdx.z * (size_t)gridDim.y * 128 * N;
        #pragma unroll
        for (int mh = 0; mh < 2; ++mh)
            #pragma unroll
            for (int i = 0; i < 4; ++i) {
                size_t gm = (size_t)(mblk + mh * 64 + tm + i);
                #pragma unroll
                for (int nh = 0; nh < 2; ++nh) {
                    int gn = nblk + nh * 64 + tn;
                    float4 r;
                    r.x = acc[mh][nh][i][0]; r.y = acc[mh][nh][i][1];
                    r.z = acc[mh][nh][i][2]; r.w = acc[mh][nh][i][3];
                    *reinterpret_cast<float4*>(&P[gm * (size_t)N + gn]) = r;
                }
            }
    }
}

// ---------------------------------------------------------------------------
// Attention: sum xd partials (+fc1_b), scores -> softmax -> alpha
__global__ __launch_bounds__(256)
void attn_kernel(const float* __restrict__ x_enc, const float* __restrict__ xdp,
                 int nparts, const float* __restrict__ fc1_b,
                 const float* __restrict__ score_w, const float* __restrict__ score_b,
                 float* __restrict__ alpha_ws, float* __restrict__ out_alpha, int t)
{
    __shared__ float lds_xd[AA];
    __shared__ float lds_sw[AA];
    __shared__ float part[LL][4];
    int b = blockIdx.x, tid = threadIdx.x;
    for (int j = tid; j < AA; j += 256) {
        float s = fc1_b[j];
        for (int p = 0; p < nparts; ++p)
            s += xdp[((size_t)p * BB + b) * AA + j];
        lds_xd[j] = s;
        lds_sw[j] = score_w[j];
    }
    __syncthreads();
    int l = tid >> 2, q = tid & 3;               // 64 rows x 4 partials
    const float* xr = x_enc + ((size_t)(b * LL) + l) * AA + q * 128;
    float s = 0.f;
    #pragma unroll 4
    for (int j = 0; j < 128; ++j)
        s += tanhf(xr[j] + lds_xd[q * 128 + j]) * lds_sw[q * 128 + j];
    part[l][q] = s;
    __syncthreads();
    if (tid < 64) {   // lanes 0..63 = wave 0
        float sc = part[tid][0] + part[tid][1] + part[tid][2] + part[tid][3] + score_b[0];
        float m = sc;
        for (int off = 32; off; off >>= 1) m = fmaxf(m, __shfl_xor(m, off));
        float e = expf(sc - m);
        float sum = e;
        for (int off = 32; off; off >>= 1) sum += __shfl_xor(sum, off);
        float al = e / sum;
        alpha_ws[b * LL + tid] = al;
        out_alpha[((size_t)b * TT + t) * LL + tid] = al;
    }
}

// ---------------------------------------------------------------------------
// context[b,f] = sum_l X[b,l,f] * alpha[b,l]
__global__ __launch_bounds__(256)
void context_kernel(const float* __restrict__ X, const float* __restrict__ alpha,
                    float* __restrict__ context)
{
    int idx = blockIdx.x * 256 + threadIdx.x;  // over B*F
    int b = idx >> 11, f = idx & (FF - 1);
    const float* xp = X + (size_t)b * LL * FF + f;
    const float* al = alpha + b * LL;
    float s = 0.f;
    #pragma unroll
    for (int l = 0; l < LL; ++l) s = fmaf(xp[l * FF], al[l], s);
    context[idx] = s;
}

// ---------------------------------------------------------------------------
// LSTM pointwise: sum gate partials + biases, update h,c in place
__global__ __launch_bounds__(256)
void lstm_kernel(const float* __restrict__ gp, int nparts,
                 const float* __restrict__ b_ih, const float* __restrict__ b_hh,
                 float* __restrict__ h, float* __restrict__ c)
{
    int idx = blockIdx.x * 256 + threadIdx.x;  // over B*H
    int b = idx >> 10, n = idx & (HH - 1);
    float gi = b_ih[n]          + b_hh[n];
    float gf = b_ih[HH + n]     + b_hh[HH + n];
    float gg = b_ih[2 * HH + n] + b_hh[2 * HH + n];
    float go = b_ih[3 * HH + n] + b_hh[3 * HH + n];
    for (int p = 0; p < nparts; ++p) {
        const float* g = gp + ((size_t)p * BB + b) * 4 * HH;
        gi += g[n]; gf += g[HH + n]; gg += g[2 * HH + n]; go += g[3 * HH + n];
    }
    float si = 1.f / (1.f + expf(-gi));
    float sf = 1.f / (1.f + expf(-gf));
    float so = 1.f / (1.f + expf(-go));
    float c2 = sf * c[idx] + si * tanhf(gg);
    float h2 = so * tanhf(c2);
    c[idx] = c2;
    h[idx] = h2;
}

// ---------------------------------------------------------------------------
// h0/c0 reduce: sum partials of [128][2048] (cols 0..1023 -> h, 1024.. -> c)
__global__ __launch_bounds__(256)
void hc0_reduce(const float* __restrict__ part, int nparts,
                const float* __restrict__ sm_b, const float* __restrict__ lm_b,
                float* __restrict__ h, float* __restrict__ c)
{
    int idx = blockIdx.x * 256 + threadIdx.x;  // over B*2048
    int b = idx >> 11, n = idx & 2047;
    float s = 0.f;
    for (int p = 0; p < nparts; ++p)
        s += part[((size_t)p * BB + b) * 2048 + n];
    if (n < HH) h[(size_t)b * HH + n] = s + sm_b[n];
    else        c[(size_t)b * HH + (n - HH)] = s + lm_b[n - HH];
}

// ---------------------------------------------------------------------------
extern "C" void kernel_launch(void* const* d_in, const int* in_sizes, int n_in,
                              void* d_out, int out_size, void* d_ws, size_t ws_size,
                              hipStream_t stream) {
    const float* X       = (const float*)d_in[0];
    const int*   y       = (const int*)d_in[1];
    const float* emb     = (const float*)d_in[2];
    const float* fc1_w   = (const float*)d_in[3];
    const float* fc1_b   = (const float*)d_in[4];
    const float* fc2_w   = (const float*)d_in[5];
    const float* fc2_b   = (const float*)d_in[6];
    const float* score_w = (const float*)d_in[7];
    const float* score_b = (const float*)d_in[8];
    const float* sm_w    = (const float*)d_in[9];
    const float* sm_b    = (const float*)d_in[10];
    const float* lm_w    = (const float*)d_in[11];
    const float* lm_b    = (const float*)d_in[12];
    const float* w_ih    = (const float*)d_in[13];
    const float* b_ih    = (const float*)d_in[14];
    const float* w_hh    = (const float*)d_in[15];
    const float* b_hh    = (const float*)d_in[16];
    const float* out_w   = (const float*)d_in[17];
    const float* out_b   = (const float*)d_in[18];

    float* out = (float*)d_out;
    float* out_alpha = out + (size_t)BB * TT * VV;   // outputs then weights, flat

    float* ws = (float*)d_ws;
    float* mean_ann = ws;  ws += (size_t)BB * FF;
    float* hbuf     = ws;  ws += (size_t)BB * HH;
    float* cbuf     = ws;  ws += (size_t)BB * HH;
    float* x_enc    = ws;  ws += (size_t)BB * LL * AA;
    float* alpha    = ws;  ws += (size_t)BB * LL;
    float* context  = ws;  ws += (size_t)BB * FF;
    float* parts    = ws;  // shared K-split partial region (time-multiplexed)

    size_t fixed_f = (size_t)(parts - (float*)d_ws);
    size_t avail_f = ws_size / sizeof(float) > fixed_f ? ws_size / sizeof(float) - fixed_f : 0;

    // pick K-split factors that fit the workspace (chunks must be %32 == 0)
    int KSg = 1;                                   // gates: K = 3584
    if      (avail_f >= (size_t)16 * BB * 4 * HH) KSg = 16;   // 33.5 MB
    else if (avail_f >= (size_t)8  * BB * 4 * HH) KSg = 8;
    else if (avail_f >= (size_t)4  * BB * 4 * HH) KSg = 4;
    else if (avail_f >= (size_t)2  * BB * 4 * HH) KSg = 2;
    int KSx = 8;                                   // xd: K = 1024
    if      (avail_f >= (size_t)32 * BB * AA) KSx = 32;
    else if (avail_f >= (size_t)16 * BB * AA) KSx = 16;
    int KSh = (avail_f >= (size_t)8 * BB * 2 * HH) ? 8 : 2;   // h0c0: K = 2048

    // --- precompute ---
    mean_kernel<<<BB * FF / 256, 256, 0, stream>>>(X, mean_ann);
    // h0|c0 partials = mean_ann @ [sm_w | lm_w]   [128,2048]x[2048,2048]
    gemm128<3><<<dim3(2 * HH / 128, 1, KSh), 256, 0, stream>>>(
        mean_ann, nullptr, nullptr, nullptr, nullptr, 0,
        sm_w, lm_w, nullptr, parts, 2 * HH, FF, 0);
    hc0_reduce<<<BB * 2 * HH / 256, 256, 0, stream>>>(parts, KSh, sm_b, lm_b, hbuf, cbuf);
    // x_enc = X @ fc2_w + fc2_b   [8192,2048]x[2048,512]
    gemm128<0><<<dim3(AA / 128, BB * LL / 128, 1), 256, 0, stream>>>(
        X, nullptr, nullptr, nullptr, nullptr, 0,
        fc2_w, nullptr, fc2_b, x_enc, AA, FF, AA);

    // --- decode loop ---
    for (int t = 0; t < TT; ++t) {
        // xd partials = h @ fc1_w   [128,1024]x[1024,512]
        gemm128<0><<<dim3(AA / 128, 1, KSx), 256, 0, stream>>>(
            hbuf, nullptr, nullptr, nullptr, nullptr, 0,
            fc1_w, nullptr, nullptr, parts, AA, HH, 0);
        // attention softmax + alpha output (sums xd partials + fc1_b)
        attn_kernel<<<BB, 256, 0, stream>>>(x_enc, parts, KSx, fc1_b,
                                            score_w, score_b, alpha, out_alpha, t);
        // context = alpha @ X
        context_kernel<<<BB * FF / 256, 256, 0, stream>>>(X, alpha, context);
        // gates partials = [emb_t | context | h] @ [w_ih ; w_hh]   K=3584, N=4096
        gemm128<2><<<dim3(4 * HH / 128, 1, KSg), 256, 0, stream>>>(
            nullptr, context, hbuf, emb, y, t,
            w_ih, w_hh, nullptr, parts, 4 * HH, EE + FF + HH, 0);
        // LSTM pointwise (sums gate partials + biases) -> h,c updated in place
        lstm_kernel<<<BB * HH / 256, 256, 0, stream>>>(parts, KSg, b_ih, b_hh, hbuf, cbuf);
        // logits = h2 @ out_w + out_b   [128,1024]x[1024,32000]
        gemm128<0><<<dim3(VV / 128, 1, 1), 256, 0, stream>>>(
            hbuf, nullptr, nullptr, nullptr, nullptr, 0,
            out_w, nullptr, out_b, out + (size_t)t * VV, VV, HH, TT * VV);
    }
}